// Round 3
// baseline (336.044 us; speedup 1.0000x reference)
//
#include <hip/hip_runtime.h>
#include <hip/hip_bf16.h>

#define B_ROWS 8192
#define D_DIM  2048
#define C_DIM  1000
#define C_PAD  1024

#define EPS32   1.1920928955078125e-07f
#define GAMMA_F 3.7200759760208361e-44f   // 1/exp(100), fp32 denormal

typedef __attribute__((ext_vector_type(8))) short short8;   // 8 bf16 = 4 VGPRs
typedef __attribute__((ext_vector_type(4))) float f32x4;    // MFMA accumulator

#define GLOAD_LDS16(gptr, lptr) \
  __builtin_amdgcn_global_load_lds((const __attribute__((address_space(1))) void*)(gptr), \
                                   (__attribute__((address_space(3))) void*)(lptr), 16, 0, 0)

__device__ inline unsigned short f2bf(float x) {
  union { __hip_bfloat16 b; unsigned short u; } cv;
  cv.b = __float2bfloat16(x);
  return cv.u;
}

__device__ inline float wave_red(float v) {
#pragma unroll
  for (int off = 32; off > 0; off >>= 1) v += __shfl_down(v, off, 64);
  return v;
}

// ---- P: merged prep.
//   blocks [0,1024):    cast cls_w [1000,2048] f32 -> bf16 padded to [1024,2048]
//   blocks [1024,3072): LDS-tiled transpose ywtb[t][d] = y_w[d][t] + y_b[d]
//   block 0 thread 0 additionally zeroes the loss accumulator slot.
__global__ __launch_bounds__(256) void prep(const float* __restrict__ cls_w,
                                            const float* __restrict__ y_w,
                                            const float* __restrict__ y_b,
                                            __hip_bfloat16* __restrict__ clsw_bf,
                                            float* __restrict__ ywtb,
                                            float* __restrict__ out_loss) {
  __shared__ float tile[32][33];
  int bid = blockIdx.x;
  if (bid == 0 && threadIdx.x == 0) out_loss[0] = 0.f;
  if (bid < 1024) {
    int j = (bid * 256 + threadIdx.x) * 8;   // element idx in padded [1024][2048]
    int row = j >> 11;
    int col = j & 2047;
    union { unsigned short u[8]; uint4 v; } pk;
    if (row < C_DIM) {
      const float* src = cls_w + (size_t)row * D_DIM + col;
#pragma unroll
      for (int i = 0; i < 8; ++i) pk.u[i] = f2bf(src[i]);
    } else {
#pragma unroll
      for (int i = 0; i < 8; ++i) pk.u[i] = 0;
    }
    *(uint4*)((unsigned short*)clsw_bf + j) = pk.v;
  } else {
    int b2 = bid - 1024;
    int tb = b2 & 31, db = b2 >> 5;          // t-tile 0..31, d-tile 0..63
    int t0 = tb * 32, d0 = db * 32;
    int tx = threadIdx.x & 31, ty = threadIdx.x >> 5;   // tx 0..31, ty 0..7
#pragma unroll
    for (int r = 0; r < 4; ++r) {
      int d = d0 + ty + r * 8;
      int t = t0 + tx;
      tile[ty + r * 8][tx] = (t < C_DIM) ? y_w[(size_t)d * C_DIM + t] : 0.f;
    }
    __syncthreads();
#pragma unroll
    for (int r = 0; r < 4; ++r) {
      int t = t0 + ty + r * 8;
      int d = d0 + tx;
      if (t < C_DIM) ywtb[(size_t)t * D_DIM + d] = tile[tx][ty + r * 8] + y_b[d];
    }
  }
}

// ---- B: z = feature + eps (store bf16 for GEMM); rex[b] = 0.5*(sum((z-yemb)^2) - sum((z-f)^2))
__global__ __launch_bounds__(256) void fuse_z(const float* __restrict__ feature,
                                              const float* __restrict__ eps,
                                              const float* __restrict__ ywtb,
                                              const int* __restrict__ target,
                                              __hip_bfloat16* __restrict__ z_bf,
                                              float* __restrict__ rex) {
  int b = blockIdx.x;
  int tid = threadIdx.x;
  int t = target[b];
  const float4* f4 = (const float4*)(feature + (size_t)b * D_DIM);
  const float4* e4 = (const float4*)(eps + (size_t)b * D_DIM);
  const float4* y4 = (const float4*)(ywtb + (size_t)t * D_DIM);
  uint2* zrow = (uint2*)((unsigned short*)z_bf + (size_t)b * D_DIM);

  float se = 0.f, sd = 0.f;
#pragma unroll
  for (int i = 0; i < 2; ++i) {
    int idx = tid + i * 256;
    float4 f = f4[idx];
    float4 e = e4[idx];
    float4 y = y4[idx];
    float z0 = f.x + e.x, z1 = f.y + e.y, z2 = f.z + e.z, z3 = f.w + e.w;
    union { unsigned short u[4]; uint2 v; } pz;
    pz.u[0] = f2bf(z0); pz.u[1] = f2bf(z1); pz.u[2] = f2bf(z2); pz.u[3] = f2bf(z3);
    zrow[idx] = pz.v;
    float a0 = z0 - f.x, a1 = z1 - f.y, a2 = z2 - f.z, a3 = z3 - f.w;
    se += a0 * a0 + a1 * a1 + a2 * a2 + a3 * a3;
    float g0 = z0 - y.x, g1 = z1 - y.y, g2 = z2 - y.z, g3 = z3 - y.w;
    sd += g0 * g0 + g1 * g1 + g2 * g2 + g3 * g3;
  }
  se = wave_red(se);
  sd = wave_red(sd);
  __shared__ float s1[4], s2[4];
  int lane = tid & 63, w = tid >> 6;
  if (lane == 0) { s1[w] = se; s2[w] = sd; }
  __syncthreads();
  if (tid == 0) {
    float S1 = s1[0] + s1[1] + s1[2] + s1[3];
    float S2 = s2[0] + s2[1] + s2[2] + s2[3];
    rex[b] = 0.5f * (S2 - S1);
  }
}

// ---- C: probs_raw = z @ cls_w^T + cls_b
// 128x128 tile, BK=64, 4 waves x (4x4) 16x16x32 MFMA.
// LDS layout XOR-swizzled: 16B chunk (row, cc) lives at slot row*8 + (cc ^ (row&7)).
// This keeps global_load_lds's lane-contiguous dest while making the
// fragment reads (16 rows at fixed cc) hit 8 distinct bank groups x 2-way (free).
__global__ __launch_bounds__(256) void gemm_bt(const __hip_bfloat16* __restrict__ A,
                                               const __hip_bfloat16* __restrict__ Bt,
                                               const float* __restrict__ cls_b,
                                               float* __restrict__ out) {
  __shared__ __align__(16) __hip_bfloat16 sA[128 * 64];
  __shared__ __align__(16) __hip_bfloat16 sB[128 * 64];
  const int tid = threadIdx.x;
  const int m0 = blockIdx.x * 128;
  const int n0 = blockIdx.y * 128;
  const int w = tid >> 6, lane = tid & 63;
  const int wm = (w & 1) * 64, wn = (w >> 1) * 64;
  const int l15 = lane & 15, quad = lane >> 4;

  f32x4 acc[4][4] = {};

  for (int k0 = 0; k0 < D_DIM; k0 += 64) {
#pragma unroll
    for (int i = 0; i < 4; ++i) {
      int j = i * 256 + tid;          // LDS slot: 1024 chunks of 16B per 128x64 tile
      int row = j >> 3;
      int cc = (j & 7) ^ (row & 7);   // inverse of the swizzle (XOR is an involution)
      const __hip_bfloat16* srcA = A + (size_t)(m0 + row) * D_DIM + k0 + cc * 8;
      const __hip_bfloat16* srcB = Bt + (size_t)(n0 + row) * D_DIM + k0 + cc * 8;
      GLOAD_LDS16(srcA, &sA[j * 8]);
      GLOAD_LDS16(srcB, &sB[j * 8]);
    }
    __syncthreads();
#pragma unroll
    for (int kk = 0; kk < 64; kk += 32) {
      const int ccr = (kk >> 3) + quad;   // which 8-elem chunk along K
      short8 af[4], bfr[4];
#pragma unroll
      for (int i = 0; i < 4; ++i) {
        int r = wm + i * 16 + l15;
        af[i] = *(const short8*)&sA[(r * 8 + (ccr ^ (r & 7))) * 8];
      }
#pragma unroll
      for (int jn = 0; jn < 4; ++jn) {
        int r = wn + jn * 16 + l15;
        bfr[jn] = *(const short8*)&sB[(r * 8 + (ccr ^ (r & 7))) * 8];
      }
#pragma unroll
      for (int i = 0; i < 4; ++i)
#pragma unroll
        for (int jn = 0; jn < 4; ++jn)
          acc[i][jn] = __builtin_amdgcn_mfma_f32_16x16x32_bf16(af[i], bfr[jn], acc[i][jn], 0, 0, 0);
    }
    __syncthreads();
  }

  // epilogue: C/D layout col=lane&15, row=quad*4+reg  (m89-verified)
#pragma unroll
  for (int i = 0; i < 4; ++i) {
    int row = m0 + wm + i * 16 + quad * 4;
#pragma unroll
    for (int jn = 0; jn < 4; ++jn) {
      int col = n0 + wn + jn * 16 + l15;
      if (col < C_DIM) {
        float bias = cls_b[col];
#pragma unroll
        for (int r = 0; r < 4; ++r)
          out[(size_t)(row + r) * C_DIM + col] = acc[i][jn][r] + bias;
      }
    }
  }
}

// ---- D: per-row normalize + clamp + log (in-place on d_out);
//         loss += (GAMMA*rex + h3)/B  via one atomicAdd per block
__global__ __launch_bounds__(256) void rownorm(float* __restrict__ out,
                                               const int* __restrict__ target,
                                               const float* __restrict__ rex,
                                               float* __restrict__ out_loss) {
  int b = blockIdx.x, tid = threadIdx.x;
  float* row = out + (size_t)b * C_DIM;
  float v[4];
  float s = 0.f;
#pragma unroll
  for (int i = 0; i < 4; ++i) {
    int c = tid + i * 256;
    v[i] = (c < C_DIM) ? row[c] : 0.f;
    s += v[i];
  }
  s = wave_red(s);
  __shared__ float ws_[4];
  __shared__ float h3s;
  int lane = tid & 63, w = tid >> 6;
  if (lane == 0) ws_[w] = s;
  __syncthreads();
  float total = ws_[0] + ws_[1] + ws_[2] + ws_[3];
  float inv = 1.0f / total;
  int t = target[b];
#pragma unroll
  for (int i = 0; i < 4; ++i) {
    int c = tid + i * 256;
    if (c < C_DIM) {
      float p = v[i] * inv;
      p = fminf(fmaxf(p, EPS32), 1.0f - EPS32);
      float lg = __logf(p);
      row[c] = lg;
      if (c == t) h3s = -lg;
    }
  }
  __syncthreads();
  if (tid == 0) {
    float rowloss = fmaf(GAMMA_F, rex[b], h3s);
    atomicAdd(out_loss, rowloss * (1.0f / B_ROWS));
  }
}

extern "C" void kernel_launch(void* const* d_in, const int* in_sizes, int n_in,
                              void* d_out, int out_size, void* d_ws, size_t ws_size,
                              hipStream_t stream) {
  const float* feature = (const float*)d_in[0];
  const float* y_w     = (const float*)d_in[1];
  const float* y_b     = (const float*)d_in[2];
  const float* cls_w   = (const float*)d_in[3];
  const float* cls_b   = (const float*)d_in[4];
  const float* eps     = (const float*)d_in[5];
  const int*   target  = (const int*)d_in[6];
  float* out = (float*)d_out;
  float* out_loss = out + (size_t)B_ROWS * C_DIM;

  char* ws = (char*)d_ws;
  __hip_bfloat16* z_bf    = (__hip_bfloat16*)ws;                               // 8192*2048*2 = 33554432 B
  __hip_bfloat16* clsw_bf = (__hip_bfloat16*)(ws + 33554432);                  // 1024*2048*2 =  4194304 B
  float*          ywtb    = (float*)(ws + 33554432 + 4194304);                 // 1000*2048*4 =  8192000 B
  float*          rex     = (float*)(ws + 33554432 + 4194304 + 8192000);       // 8192*4      =    32768 B

  prep<<<dim3(1024 + 2048), 256, 0, stream>>>(cls_w, y_w, y_b, clsw_bf, ywtb, out_loss);
  fuse_z<<<dim3(B_ROWS), 256, 0, stream>>>(feature, eps, ywtb, target, z_bf, rex);
  gemm_bt<<<dim3(B_ROWS / 128, C_PAD / 128), 256, 0, stream>>>(z_bf, clsw_bf, cls_b, out);
  rownorm<<<dim3(B_ROWS), 256, 0, stream>>>(out, target, rex, out_loss);
}

// Round 4
// 243.504 us; speedup vs baseline: 1.3800x; 1.3800x over previous
//
#include <hip/hip_runtime.h>
#include <hip/hip_bf16.h>

#define B_ROWS 8192
#define D_DIM  2048
#define C_DIM  1000
#define C_PAD  1024

#define EPS32   1.1920928955078125e-07f
#define GAMMA_F 3.7200759760208361e-44f   // 1/exp(100), fp32 denormal

typedef __attribute__((ext_vector_type(8))) short short8;   // 8 bf16 = 4 VGPRs
typedef __attribute__((ext_vector_type(4))) float f32x4;    // MFMA accumulator

#define GLOAD_LDS16(gptr, lptr) \
  __builtin_amdgcn_global_load_lds((const __attribute__((address_space(1))) void*)(gptr), \
                                   (__attribute__((address_space(3))) void*)(lptr), 16, 0, 0)

__device__ inline unsigned short f2bf(float x) {
  union { __hip_bfloat16 b; unsigned short u; } cv;
  cv.b = __float2bfloat16(x);
  return cv.u;
}

__device__ inline float wave_red(float v) {
#pragma unroll
  for (int off = 32; off > 0; off >>= 1) v += __shfl_down(v, off, 64);
  return v;
}

// ---- P: merged prep.
//   blocks [0,1024):    cast cls_w [1000,2048] f32 -> bf16 padded to [1024,2048]
//   blocks [1024,3072): LDS-tiled transpose ywtb[t][d] = y_w[d][t] + y_b[d]
__global__ __launch_bounds__(256) void prep(const float* __restrict__ cls_w,
                                            const float* __restrict__ y_w,
                                            const float* __restrict__ y_b,
                                            __hip_bfloat16* __restrict__ clsw_bf,
                                            float* __restrict__ ywtb) {
  __shared__ float tile[32][33];
  int bid = blockIdx.x;
  if (bid < 1024) {
    int j = (bid * 256 + threadIdx.x) * 8;   // element idx in padded [1024][2048]
    int row = j >> 11;
    int col = j & 2047;
    union { unsigned short u[8]; uint4 v; } pk;
    if (row < C_DIM) {
      const float* src = cls_w + (size_t)row * D_DIM + col;
#pragma unroll
      for (int i = 0; i < 8; ++i) pk.u[i] = f2bf(src[i]);
    } else {
#pragma unroll
      for (int i = 0; i < 8; ++i) pk.u[i] = 0;
    }
    *(uint4*)((unsigned short*)clsw_bf + j) = pk.v;
  } else {
    int b2 = bid - 1024;
    int tb = b2 & 31, db = b2 >> 5;          // t-tile 0..31, d-tile 0..63
    int t0 = tb * 32, d0 = db * 32;
    int tx = threadIdx.x & 31, ty = threadIdx.x >> 5;   // tx 0..31, ty 0..7
#pragma unroll
    for (int r = 0; r < 4; ++r) {
      int d = d0 + ty + r * 8;
      int t = t0 + tx;
      tile[ty + r * 8][tx] = (t < C_DIM) ? y_w[(size_t)d * C_DIM + t] : 0.f;
    }
    __syncthreads();
#pragma unroll
    for (int r = 0; r < 4; ++r) {
      int t = t0 + ty + r * 8;
      int d = d0 + tx;
      if (t < C_DIM) ywtb[(size_t)t * D_DIM + d] = tile[tx][ty + r * 8] + y_b[d];
    }
  }
}

// ---- B: z = feature + eps (store bf16 for GEMM); rex[b] = 0.5*(sum((z-yemb)^2) - sum((z-f)^2))
__global__ __launch_bounds__(256) void fuse_z(const float* __restrict__ feature,
                                              const float* __restrict__ eps,
                                              const float* __restrict__ ywtb,
                                              const int* __restrict__ target,
                                              __hip_bfloat16* __restrict__ z_bf,
                                              float* __restrict__ rex) {
  int b = blockIdx.x;
  int tid = threadIdx.x;
  int t = target[b];
  const float4* f4 = (const float4*)(feature + (size_t)b * D_DIM);
  const float4* e4 = (const float4*)(eps + (size_t)b * D_DIM);
  const float4* y4 = (const float4*)(ywtb + (size_t)t * D_DIM);
  uint2* zrow = (uint2*)((unsigned short*)z_bf + (size_t)b * D_DIM);

  float se = 0.f, sd = 0.f;
#pragma unroll
  for (int i = 0; i < 2; ++i) {
    int idx = tid + i * 256;
    float4 f = f4[idx];
    float4 e = e4[idx];
    float4 y = y4[idx];
    float z0 = f.x + e.x, z1 = f.y + e.y, z2 = f.z + e.z, z3 = f.w + e.w;
    union { unsigned short u[4]; uint2 v; } pz;
    pz.u[0] = f2bf(z0); pz.u[1] = f2bf(z1); pz.u[2] = f2bf(z2); pz.u[3] = f2bf(z3);
    zrow[idx] = pz.v;
    float a0 = z0 - f.x, a1 = z1 - f.y, a2 = z2 - f.z, a3 = z3 - f.w;
    se += a0 * a0 + a1 * a1 + a2 * a2 + a3 * a3;
    float g0 = z0 - y.x, g1 = z1 - y.y, g2 = z2 - y.z, g3 = z3 - y.w;
    sd += g0 * g0 + g1 * g1 + g2 * g2 + g3 * g3;
  }
  se = wave_red(se);
  sd = wave_red(sd);
  __shared__ float s1[4], s2[4];
  int lane = tid & 63, w = tid >> 6;
  if (lane == 0) { s1[w] = se; s2[w] = sd; }
  __syncthreads();
  if (tid == 0) {
    float S1 = s1[0] + s1[1] + s1[2] + s1[3];
    float S2 = s2[0] + s2[1] + s2[2] + s2[3];
    rex[b] = 0.5f * (S2 - S1);
  }
}

// ---- C: probs_raw = z @ cls_w^T + cls_b
// 128x128 tile, BK=64, 4 waves x (4x4) 16x16x32 MFMA.
// LDS layout XOR-swizzled: 16B chunk (row, cc) lives at slot row*8 + (cc ^ (row&7)).
__global__ __launch_bounds__(256) void gemm_bt(const __hip_bfloat16* __restrict__ A,
                                               const __hip_bfloat16* __restrict__ Bt,
                                               const float* __restrict__ cls_b,
                                               float* __restrict__ out) {
  __shared__ __align__(16) __hip_bfloat16 sA[128 * 64];
  __shared__ __align__(16) __hip_bfloat16 sB[128 * 64];
  const int tid = threadIdx.x;
  const int m0 = blockIdx.x * 128;
  const int n0 = blockIdx.y * 128;
  const int w = tid >> 6, lane = tid & 63;
  const int wm = (w & 1) * 64, wn = (w >> 1) * 64;
  const int l15 = lane & 15, quad = lane >> 4;

  f32x4 acc[4][4] = {};

  for (int k0 = 0; k0 < D_DIM; k0 += 64) {
#pragma unroll
    for (int i = 0; i < 4; ++i) {
      int j = i * 256 + tid;          // LDS slot: 1024 chunks of 16B per 128x64 tile
      int row = j >> 3;
      int cc = (j & 7) ^ (row & 7);   // inverse of the swizzle (XOR is an involution)
      const __hip_bfloat16* srcA = A + (size_t)(m0 + row) * D_DIM + k0 + cc * 8;
      const __hip_bfloat16* srcB = Bt + (size_t)(n0 + row) * D_DIM + k0 + cc * 8;
      GLOAD_LDS16(srcA, &sA[j * 8]);
      GLOAD_LDS16(srcB, &sB[j * 8]);
    }
    __syncthreads();
#pragma unroll
    for (int kk = 0; kk < 64; kk += 32) {
      const int ccr = (kk >> 3) + quad;   // which 8-elem chunk along K
      short8 af[4], bfr[4];
#pragma unroll
      for (int i = 0; i < 4; ++i) {
        int r = wm + i * 16 + l15;
        af[i] = *(const short8*)&sA[(r * 8 + (ccr ^ (r & 7))) * 8];
      }
#pragma unroll
      for (int jn = 0; jn < 4; ++jn) {
        int r = wn + jn * 16 + l15;
        bfr[jn] = *(const short8*)&sB[(r * 8 + (ccr ^ (r & 7))) * 8];
      }
#pragma unroll
      for (int i = 0; i < 4; ++i)
#pragma unroll
        for (int jn = 0; jn < 4; ++jn)
          acc[i][jn] = __builtin_amdgcn_mfma_f32_16x16x32_bf16(af[i], bfr[jn], acc[i][jn], 0, 0, 0);
    }
    __syncthreads();
  }

  // epilogue: C/D layout col=lane&15, row=quad*4+reg  (m89-verified)
#pragma unroll
  for (int i = 0; i < 4; ++i) {
    int row = m0 + wm + i * 16 + quad * 4;
#pragma unroll
    for (int jn = 0; jn < 4; ++jn) {
      int col = n0 + wn + jn * 16 + l15;
      if (col < C_DIM) {
        float bias = cls_b[col];
#pragma unroll
        for (int r = 0; r < 4; ++r)
          out[(size_t)(row + r) * C_DIM + col] = acc[i][jn][r] + bias;
      }
    }
  }
}

// ---- D: wave-autonomous per-row normalize+clamp+log. One wave per row; lane
// owns 16 cols as 4 float4 chunks. Row sum = pure shuffle reduce (no LDS, no
// barrier). rowloss[b] = GAMMA*rex[b] + h3 written by the lane owning col t.
__global__ __launch_bounds__(256) void rownorm(float* __restrict__ out,
                                               const int* __restrict__ target,
                                               const float* __restrict__ rex,
                                               float* __restrict__ rowloss) {
  int b = blockIdx.x * 4 + (threadIdx.x >> 6);
  int lane = threadIdx.x & 63;
  float* row = out + (size_t)b * C_DIM;

  float v[16];
  float s = 0.f;
#pragma unroll
  for (int k = 0; k < 4; ++k) {
    int c = k * 256 + lane * 4;
    if (c + 3 < C_DIM) {
      float4 f = *(const float4*)(row + c);
      v[k * 4 + 0] = f.x; v[k * 4 + 1] = f.y; v[k * 4 + 2] = f.z; v[k * 4 + 3] = f.w;
    } else {
#pragma unroll
      for (int i = 0; i < 4; ++i) v[k * 4 + i] = (c + i < C_DIM) ? row[c + i] : 0.f;
    }
    s += v[k * 4 + 0] + v[k * 4 + 1] + v[k * 4 + 2] + v[k * 4 + 3];
  }
  s = wave_red(s);
  float inv = 1.0f / __shfl(s, 0, 64);
  int t = target[b];
  float rexb = rex[b];

#pragma unroll
  for (int k = 0; k < 4; ++k) {
    int c = k * 256 + lane * 4;
    float lg[4];
#pragma unroll
    for (int i = 0; i < 4; ++i) {
      float p = v[k * 4 + i] * inv;
      p = fminf(fmaxf(p, EPS32), 1.0f - EPS32);
      lg[i] = __logf(p);
      if (c + i == t) rowloss[b] = fmaf(GAMMA_F, rexb, -lg[i]);
    }
    if (c + 3 < C_DIM) {
      *(float4*)(row + c) = make_float4(lg[0], lg[1], lg[2], lg[3]);
    } else {
#pragma unroll
      for (int i = 0; i < 4; ++i) if (c + i < C_DIM) row[c + i] = lg[i];
    }
  }
}

// ---- E: loss = mean(rowloss)
__global__ __launch_bounds__(256) void finalize(const float* __restrict__ rowloss,
                                                float* __restrict__ out_loss) {
  int tid = threadIdx.x;
  float s = 0.f;
  for (int i = tid; i < B_ROWS; i += 256) s += rowloss[i];
  s = wave_red(s);
  __shared__ float sm[4];
  if ((tid & 63) == 0) sm[tid >> 6] = s;
  __syncthreads();
  if (tid == 0) out_loss[0] = (sm[0] + sm[1] + sm[2] + sm[3]) * (1.0f / B_ROWS);
}

extern "C" void kernel_launch(void* const* d_in, const int* in_sizes, int n_in,
                              void* d_out, int out_size, void* d_ws, size_t ws_size,
                              hipStream_t stream) {
  const float* feature = (const float*)d_in[0];
  const float* y_w     = (const float*)d_in[1];
  const float* y_b     = (const float*)d_in[2];
  const float* cls_w   = (const float*)d_in[3];
  const float* cls_b   = (const float*)d_in[4];
  const float* eps     = (const float*)d_in[5];
  const int*   target  = (const int*)d_in[6];
  float* out = (float*)d_out;
  float* out_loss = out + (size_t)B_ROWS * C_DIM;

  char* ws = (char*)d_ws;
  __hip_bfloat16* z_bf    = (__hip_bfloat16*)ws;                               // 33554432 B
  __hip_bfloat16* clsw_bf = (__hip_bfloat16*)(ws + 33554432);                  //  4194304 B
  float*          ywtb    = (float*)(ws + 33554432 + 4194304);                 //  8192000 B
  float*          rex     = (float*)(ws + 33554432 + 4194304 + 8192000);       //    32768 B
  float*          rowloss = (float*)(ws + 33554432 + 4194304 + 8192000 + 32768); // 32768 B

  prep<<<dim3(1024 + 2048), 256, 0, stream>>>(cls_w, y_w, y_b, clsw_bf, ywtb);
  fuse_z<<<dim3(B_ROWS), 256, 0, stream>>>(feature, eps, ywtb, target, z_bf, rex);
  gemm_bt<<<dim3(B_ROWS / 128, C_PAD / 128), 256, 0, stream>>>(z_bf, clsw_bf, cls_b, out);
  rownorm<<<dim3(B_ROWS / 4), 256, 0, stream>>>(out, target, rex, rowloss);
  finalize<<<dim3(1), 256, 0, stream>>>(rowloss, out_loss);
}